// Round 15
// baseline (84.619 us; speedup 1.0000x reference)
//
#include <hip/hip_runtime.h>
#include <hip/hip_bf16.h>

#define BATCH 64
#define NNODE 512
#define D_IN 768
#define FEA 256
#define HEADS 8
#define M_ROWS (BATCH * NNODE)   // 32768
#define NEG_SLOPE 0.2f
#define LOG2E 1.4426950408889634f
#define JC 8                     // j-chunks for zsum

typedef __attribute__((ext_vector_type(4))) float f32x4;
typedef __attribute__((ext_vector_type(8))) short bf16x8;

__device__ __forceinline__ ushort f2bf(float f) {
    union { float f; unsigned u; } v; v.f = f;
    unsigned r = v.u + 0x7fffu + ((v.u >> 16) & 1u);   // RNE
    return (ushort)(r >> 16);
}
__device__ __forceinline__ short f2bf_hw(float f) {
    __hip_bfloat16 h = __float2bfloat16(f);
    return *reinterpret_cast<short*>(&h);
}
__device__ __forceinline__ float exp2fast(float v) { return __builtin_amdgcn_exp2f(v); }

// P0: was[h][f] = sum_c Wg[f, h*FEA+c] * att[h,c] — 256 blocks (full CU coverage)
__global__ __launch_bounds__(256) void k_att_proj(const float* __restrict__ Wg,
                                                  const float* __restrict__ att_src,
                                                  const float* __restrict__ att_dst,
                                                  float* __restrict__ was,
                                                  float* __restrict__ wad) {
    int h = blockIdx.x;
    const float* a = (blockIdx.y == 0) ? att_src : att_dst;
    float* o = (blockIdx.y == 0) ? was : wad;
    int wv = threadIdx.x >> 6, lane = threadIdx.x & 63;
    float4 av = *(const float4*)&a[h * FEA + lane * 4];
    int fbase = blockIdx.z * 16 + wv;
    #pragma unroll
    for (int i = 0; i < 4; i++) {
        int f = fbase + i * 4;
        float4 g = *(const float4*)&Wg[(size_t)f * (HEADS * FEA) + h * FEA + lane * 4];
        float p = g.x * av.x + g.y * av.y + g.z * av.z + g.w * av.w;
        #pragma unroll
        for (int off = 32; off; off >>= 1) p += __shfl_xor(p, off);
        if (lane == 0) o[h * FEA + f] = p;
    }
}

// P1: Bpk = W1@wv packed bf16 MFMA B-frags; c_sd = b1.wv
__global__ __launch_bounds__(256) void k_prep_was1(const float* __restrict__ W1,
                                                   const float* __restrict__ b1,
                                                   const float* __restrict__ was,
                                                   const float* __restrict__ wad,
                                                   ushort* __restrict__ Bpk,
                                                   float* __restrict__ c_sd) {
    __shared__ float wvl[16 * 260];
    __shared__ float w1l[8][256];
    __shared__ float partial[256];
    int t = threadIdx.x;
    int blk = blockIdx.x;
    int k0 = blk * 8;
    for (int i = t; i < 4096; i += 256) {
        int col = i >> 8, f = i & 255;
        wvl[col * 260 + f] = (col < 8) ? was[col * 256 + f] : wad[(col - 8) * 256 + f];
    }
    for (int i = t; i < 2048; i += 256) {
        int r = i >> 8, c = i & 255;
        w1l[r][c] = W1[(size_t)(k0 + r) * 256 + c];
    }
    __syncthreads();
    int col = t & 15, r = (t >> 4) & 7, half = t >> 7;
    float acc = 0.f;
    const float* wr = &w1l[r][half * 128];
    const float* vr = &wvl[col * 260 + half * 128];
    #pragma unroll 4
    for (int f0 = 0; f0 < 128; f0 += 4) {
        float4 a4 = *(const float4*)&wr[f0];
        float4 v4 = *(const float4*)&vr[f0];
        acc += a4.x * v4.x + a4.y * v4.y + a4.z * v4.z + a4.w * v4.w;
    }
    partial[t] = acc;
    __syncthreads();
    if (t < 128) {
        float tot = partial[t] + partial[t + 128];
        int kt = blk >> 2;
        int kloc = (blk & 3) * 8 + r;
        Bpk[kt * 1024 + ((kloc >> 3) * 16 + col) * 8 + (kloc & 7)] = f2bf(tot);
    }
    if (blk == 0 && t < 16) {
        float a = 0.f;
        for (int f = 0; f < 256; f++) a += b1[f] * wvl[t * 260 + f];
        c_sd[t] = a;
    }
}

// K1: logits = (x @ Was1 + c_sd) * LOG2E — HW bf16 cast, depth-3 reg pipeline
__global__ __launch_bounds__(256) void k_logits(const float* __restrict__ x,
                                                const ushort* __restrict__ Bpk,
                                                const float* __restrict__ c_sd,
                                                float* __restrict__ a_src,
                                                float* __restrict__ a_dst) {
    int t = threadIdx.x;
    int w = t >> 6, l = t & 63;
    int lr = l & 15, lk = l >> 4;
    int row0w = blockIdx.x * 64 + w * 16;
    const float* ap = x + (size_t)(row0w + lr) * D_IN + lk * 8;
    const ushort* bp = Bpk + l * 8;

    f32x4 A0[3], A1[3];
    bf16x8 Bf[3];
    A0[0] = *(const f32x4*)(ap);      A1[0] = *(const f32x4*)(ap + 4);
    Bf[0] = *(const bf16x8*)(bp);
    A0[1] = *(const f32x4*)(ap + 32); A1[1] = *(const f32x4*)(ap + 36);
    Bf[1] = *(const bf16x8*)(bp + 1024);
    f32x4 acc = {};

    #pragma unroll
    for (int kt = 0; kt < 24; kt++) {
        int cur = kt % 3;
        if (kt + 2 < 24) {
            int nx = (kt + 2) % 3;
            A0[nx] = *(const f32x4*)(ap + (kt + 2) * 32);
            A1[nx] = *(const f32x4*)(ap + (kt + 2) * 32 + 4);
            Bf[nx] = *(const bf16x8*)(bp + (size_t)(kt + 2) * 1024);
        }
        bf16x8 af;
        af[0] = f2bf_hw(A0[cur].x); af[1] = f2bf_hw(A0[cur].y);
        af[2] = f2bf_hw(A0[cur].z); af[3] = f2bf_hw(A0[cur].w);
        af[4] = f2bf_hw(A1[cur].x); af[5] = f2bf_hw(A1[cur].y);
        af[6] = f2bf_hw(A1[cur].z); af[7] = f2bf_hw(A1[cur].w);
        acc = __builtin_amdgcn_mfma_f32_16x16x32_bf16(af, Bf[cur], acc, 0, 0, 0);
    }
    int col = lr;
    float cadd = c_sd[col];
    float* dst = (col < 8) ? a_src : a_dst;
    int h = col & 7;
    #pragma unroll
    for (int r = 0; r < 4; r++) {
        int rr = row0w + lk * 4 + r;
        int b = rr >> 9, n = rr & 511;
        dst[((size_t)(b * 8 + h) << 9) + n] = (acc[r] + cadd) * LOG2E;
    }
}

// K2: O(N log N) softmax col-sums — DUAL-bh per block (2x ILP on serial chains,
// half the barriers per row). Lifted from the verified round-9 mega P3.
__global__ __launch_bounds__(512) void k_softmax(const float* __restrict__ a_src,
                                                 const float* __restrict__ a_dst,
                                                 float* __restrict__ wout,
                                                 float* __restrict__ s_w) {
    __shared__ float Ss[1024], Ds[1024];
    __shared__ float E1[1024], E2[1024], PAa[1024], PBa[1024];
    __shared__ float red[16], tAa[16], tBa[16];
    int t = threadIdx.x;
    int lane = t & 63, wv8 = t >> 6;
    int bh0 = blockIdx.x * 2;
    float sv[2], dv[2], vs[2], vd[2], mx[2];
    #pragma unroll
    for (int u = 0; u < 2; u++) {
        sv[u] = a_src[((size_t)(bh0 + u) << 9) + t];
        dv[u] = a_dst[((size_t)(bh0 + u) << 9) + t];
        vs[u] = sv[u]; vd[u] = dv[u]; mx[u] = sv[u];
    }
    #pragma unroll
    for (int off = 32; off; off >>= 1) {
        mx[0] = fmaxf(mx[0], __shfl_xor(mx[0], off));
        mx[1] = fmaxf(mx[1], __shfl_xor(mx[1], off));
    }
    if (lane == 0) { red[wv8] = mx[0]; red[8 + wv8] = mx[1]; }
    __syncthreads();
    #pragma unroll
    for (int u = 0; u < 2; u++) {
        float m = red[u * 8];
        #pragma unroll
        for (int k = 1; k < 8; k++) m = fmaxf(m, red[u * 8 + k]);
        mx[u] = m;
    }
    // bitonic sort ascending (both bh, both arrays)
    for (int k = 2; k <= 512; k <<= 1) {
        for (int j = k >> 1; j > 0; j >>= 1) {
            bool tmin = (((t & j) == 0) == ((t & k) == 0));
            if (j >= 64) {
                __syncthreads();
                Ss[t] = vs[0]; Ss[512 + t] = vs[1];
                Ds[t] = vd[0]; Ds[512 + t] = vd[1];
                __syncthreads();
                float p0 = Ss[t ^ j], p1 = Ss[512 + (t ^ j)];
                float q0 = Ds[t ^ j], q1 = Ds[512 + (t ^ j)];
                vs[0] = tmin ? fminf(vs[0], p0) : fmaxf(vs[0], p0);
                vs[1] = tmin ? fminf(vs[1], p1) : fmaxf(vs[1], p1);
                vd[0] = tmin ? fminf(vd[0], q0) : fmaxf(vd[0], q0);
                vd[1] = tmin ? fminf(vd[1], q1) : fmaxf(vd[1], q1);
            } else {
                float p0 = __shfl_xor(vs[0], j), p1 = __shfl_xor(vs[1], j);
                float q0 = __shfl_xor(vd[0], j), q1 = __shfl_xor(vd[1], j);
                vs[0] = tmin ? fminf(vs[0], p0) : fmaxf(vs[0], p0);
                vs[1] = tmin ? fminf(vs[1], p1) : fmaxf(vs[1], p1);
                vd[0] = tmin ? fminf(vd[0], q0) : fmaxf(vd[0], q0);
                vd[1] = tmin ? fminf(vd[1], q1) : fmaxf(vd[1], q1);
            }
        }
    }
    __syncthreads();
    Ss[t] = vs[0]; Ss[512 + t] = vs[1];
    Ds[t] = vd[0]; Ds[512 + t] = vd[1];
    // E1/E2 inclusive prefix over sorted s
    float e1[2], e2[2];
    #pragma unroll
    for (int u = 0; u < 2; u++) {
        e1[u] = exp2fast(vs[u] - mx[u]);
        e2[u] = exp2fast(0.2f * (vs[u] - mx[u]));
    }
    #pragma unroll
    for (int off = 1; off < 64; off <<= 1) {
        float u10 = __shfl_up(e1[0], off), u11 = __shfl_up(e1[1], off);
        float u20 = __shfl_up(e2[0], off), u21 = __shfl_up(e2[1], off);
        if (lane >= off) { e1[0] += u10; e1[1] += u11; e2[0] += u20; e2[1] += u21; }
    }
    if (lane == 63) {
        tAa[wv8] = e1[0]; tAa[8 + wv8] = e1[1];
        tBa[wv8] = e2[0]; tBa[8 + wv8] = e2[1];
    }
    __syncthreads();
    float tot1[2], tot2[2];
    #pragma unroll
    for (int u = 0; u < 2; u++) {
        float p1 = 0.f, p2 = 0.f, s1 = 0.f, s2 = 0.f;
        #pragma unroll
        for (int k = 0; k < 8; k++) {
            float a = tAa[u * 8 + k], b = tBa[u * 8 + k];
            s1 += a; s2 += b;
            if (k < wv8) { p1 += a; p2 += b; }
        }
        e1[u] += p1; e2[u] += p2; tot1[u] = s1; tot2[u] = s2;
        E1[u * 512 + t] = e1[u]; E2[u * 512 + t] = e2[u];
    }
    __syncthreads();
    // per sorted row: L_i -> normalized pieces
    float pa[2], pb[2];
    #pragma unroll
    for (int u = 0; u < 2; u++) {
        float v = vd[u] + mx[u];
        float mi = fmaxf(v, NEG_SLOPE * v);
        float key = -vd[u];
        int lo = 0, hi = 512;
        #pragma unroll
        for (int it = 0; it < 9; it++) {
            if (lo < hi) {
                int mid = (lo + hi) >> 1;
                if (Ss[u * 512 + mid] < key) lo = mid + 1; else hi = mid;
            }
        }
        float e1pre = lo ? E1[u * 512 + lo - 1] : 0.f;
        float e2pre = lo ? E2[u * 512 + lo - 1] : 0.f;
        float ga = exp2fast(v - mi);
        float gb = exp2fast(0.2f * v - mi);
        float L = ga * (tot1[u] - e1pre) + gb * e2pre;
        float linv = 1.f / L;
        pa[u] = ga * linv; pb[u] = gb * linv;
    }
    #pragma unroll
    for (int off = 1; off < 64; off <<= 1) {
        float u10 = __shfl_up(pa[0], off), u11 = __shfl_up(pa[1], off);
        float u20 = __shfl_up(pb[0], off), u21 = __shfl_up(pb[1], off);
        if (lane >= off) { pa[0] += u10; pa[1] += u11; pb[0] += u20; pb[1] += u21; }
    }
    __syncthreads();
    if (lane == 63) {
        tAa[wv8] = pa[0]; tAa[8 + wv8] = pa[1];
        tBa[wv8] = pb[0]; tBa[8 + wv8] = pb[1];
    }
    __syncthreads();
    float totp1[2];
    #pragma unroll
    for (int u = 0; u < 2; u++) {
        float p1 = 0.f, p2 = 0.f, s1 = 0.f;
        #pragma unroll
        for (int k = 0; k < 8; k++) {
            float a = tAa[u * 8 + k], b = tBa[u * 8 + k];
            s1 += a;
            if (k < wv8) { p1 += a; p2 += b; }
        }
        pa[u] += p1; pb[u] += p2; totp1[u] = s1;
        PAa[u * 512 + t] = pa[u]; PBa[u * 512 + t] = pb[u];
    }
    __syncthreads();
    // per original column j = t
    float ssum[2];
    #pragma unroll
    for (int u = 0; u < 2; u++) {
        float key2 = -sv[u];
        int lo2 = 0, hi2 = 512;
        #pragma unroll
        for (int it = 0; it < 9; it++) {
            if (lo2 < hi2) {
                int mid = (lo2 + hi2) >> 1;
                if (Ds[u * 512 + mid] < key2) lo2 = mid + 1; else hi2 = mid;
            }
        }
        float papre = lo2 ? PAa[u * 512 + lo2 - 1] : 0.f;
        float pbpre = lo2 ? PBa[u * 512 + lo2 - 1] : 0.f;
        float e1j = exp2fast(sv[u] - mx[u]);
        float e2j = exp2fast(0.2f * (sv[u] - mx[u]));
        float wj = e1j * (totp1[u] - papre) + e2j * pbpre;
        wout[((size_t)(bh0 + u) << 9) + t] = wj;
        ssum[u] = wj;
    }
    #pragma unroll
    for (int off = 32; off; off >>= 1) {
        ssum[0] += __shfl_xor(ssum[0], off);
        ssum[1] += __shfl_xor(ssum[1], off);
    }
    __syncthreads();
    if (lane == 0) { red[wv8] = ssum[0]; red[8 + wv8] = ssum[1]; }
    __syncthreads();
    if (t == 0) {
        float a0 = 0.f, a1 = 0.f;
        #pragma unroll
        for (int k = 0; k < 8; k++) { a0 += red[k]; a1 += red[8 + k]; }
        s_w[bh0] = a0; s_w[bh0 + 1] = a1;
    }
}

// K3: z_part[(b*JC+jc)*8+h][d] = sum_{j in 64-chunk} w[b,h,j]*x[b,j,d]
// d-split x2 for occupancy: grid (64,8,2), float2/lane, 12 waves/CU
__global__ __launch_bounds__(192) void k_zsum(const float* __restrict__ w,
                                              const float* __restrict__ x,
                                              float* __restrict__ z_part) {
    __shared__ float wl[512];   // [h][64]
    int t = threadIdx.x;
    int b = blockIdx.x, jc = blockIdx.y, dh = blockIdx.z;
    for (int i = t; i < 512; i += 192) {
        int h = i >> 6, j = i & 63;
        wl[i] = w[((size_t)(b * 8 + h) << 9) + jc * 64 + j];
    }
    __syncthreads();
    float2 acc[8] = {};
    const float* xp = x + ((size_t)(b * 512 + jc * 64)) * D_IN + dh * 384 + t * 2;
    for (int j = 0; j < 64; j++) {
        float2 xv = *(const float2*)(xp + (size_t)j * D_IN);
        #pragma unroll
        for (int h = 0; h < 8; h++) {
            float wv = wl[h * 64 + j];
            acc[h].x += wv * xv.x;
            acc[h].y += wv * xv.y;
        }
    }
    #pragma unroll
    for (int h = 0; h < 8; h++)
        *(float2*)&z_part[((size_t)((b * JC + jc) * 8 + h)) * D_IN + dh * 384 + t * 2] = acc[h];
}

// K4: y_part[ds][bh][f] = sum_{d in 96-slice} z[bh,d]*W1[d,f]  (+ s_w*b1 on ds==0)
__global__ __launch_bounds__(256) void k_y(const float* __restrict__ z_part,
                                           const float* __restrict__ W1,
                                           const float* __restrict__ b1,
                                           const float* __restrict__ s_w,
                                           const float* __restrict__ bias_g,
                                           float* __restrict__ out,
                                           float* __restrict__ y_part) {
    __shared__ float zl[8][100];
    int t = threadIdx.x;
    int b = blockIdx.x, ds = blockIdx.y;
    if (ds == 0) out[b * 256 + t] = bias_g[t];
    for (int sIdx = t; sIdx < 768; sIdx += 256) {
        int k = sIdx / 96, dd = sIdx - k * 96;
        float v = 0.f;
        #pragma unroll
        for (int jc = 0; jc < JC; jc++)
            v += z_part[((size_t)((b * JC + jc) * 8 + k)) * D_IN + ds * 96 + dd];
        zl[k][dd] = v;
    }
    __syncthreads();
    float acc[8] = {};
    for (int dq = 0; dq < 24; dq++) {
        int dbase = ds * 96 + dq * 4;
        float w0 = W1[(size_t)(dbase + 0) * 256 + t];
        float w1 = W1[(size_t)(dbase + 1) * 256 + t];
        float w2 = W1[(size_t)(dbase + 2) * 256 + t];
        float w3 = W1[(size_t)(dbase + 3) * 256 + t];
        #pragma unroll
        for (int k = 0; k < 8; k++) {
            float4 zq = *(const float4*)&zl[k][dq * 4];
            acc[k] += zq.x * w0 + zq.y * w1 + zq.z * w2 + zq.w * w3;
        }
    }
    #pragma unroll
    for (int k = 0; k < 8; k++) {
        float v = acc[k];
        if (ds == 0) v += s_w[b * 8 + k] * b1[t];
        y_part[((size_t)ds * 512 + b * 8 + k) * 256 + t] = v;
    }
}

// K5: out += (1/4096)*sum_{f slice} Y[b,h,f]*Wg[f,h*256+c] — 512 blocks
__global__ __launch_bounds__(256) void k_out(const float* __restrict__ y_part,
                                             const float* __restrict__ Wg,
                                             float* __restrict__ out) {
    __shared__ float Yl[64][5];
    int t = threadIdx.x;
    int h = blockIdx.x, fs = blockIdx.y, bq = blockIdx.z;
    int f0 = fs * 64, b0 = bq * 4;
    {
        int bl = t >> 6, fl = t & 63;
        float v = 0.f;
        #pragma unroll
        for (int ds = 0; ds < 8; ds++)
            v += y_part[((size_t)(ds * 512) + (b0 + bl) * 8 + h) * 256 + f0 + fl];
        Yl[fl][bl] = v;
    }
    __syncthreads();
    float acc[4] = {};
    #pragma unroll 4
    for (int fl = 0; fl < 64; fl++) {
        float wv = Wg[(size_t)(f0 + fl) * 2048 + h * 256 + t];
        #pragma unroll
        for (int bl = 0; bl < 4; bl++) acc[bl] += Yl[fl][bl] * wv;
    }
    #pragma unroll
    for (int bl = 0; bl < 4; bl++)
        atomicAdd(&out[(b0 + bl) * 256 + t], acc[bl] * (1.f / 4096.f));
}

extern "C" void kernel_launch(void* const* d_in, const int* in_sizes, int n_in,
                              void* d_out, int out_size, void* d_ws, size_t ws_size,
                              hipStream_t stream) {
    const float* x       = (const float*)d_in[0];
    const float* W1      = (const float*)d_in[1];
    const float* b1      = (const float*)d_in[2];
    const float* Wg      = (const float*)d_in[3];
    const float* att_src = (const float*)d_in[4];
    const float* att_dst = (const float*)d_in[5];
    const float* bias_g  = (const float*)d_in[6];
    float* out = (float*)d_out;

    float* ws       = (float*)d_ws;
    float* was      = ws;                         // 2048
    float* wad      = ws + 2048;                  // 2048
    float* c_sd     = ws + 4096;                  // 16
    ushort* Bpk     = (ushort*)(ws + 4112);       // 24576 u16 = 12288 f
    float* a_src    = ws + 16400;                 // 262144
    float* a_dst    = ws + 278544;                // 262144
    float* wsum     = ws + 540688;                // 262144
    float* s_w      = ws + 802832;                // 512
    float* z_part   = ws + 803344;                // 3145728 (64*8*8*768)
    float* y_part   = ws + 3949072;               // 1048576 (8 ds slices)

    k_att_proj<<<dim3(HEADS, 2, 16), 256, 0, stream>>>(Wg, att_src, att_dst, was, wad);
    k_prep_was1<<<96, 256, 0, stream>>>(W1, b1, was, wad, Bpk, c_sd);
    k_logits<<<M_ROWS / 64, 256, 0, stream>>>(x, Bpk, c_sd, a_src, a_dst);
    k_softmax<<<BATCH * HEADS / 2, 512, 0, stream>>>(a_src, a_dst, wsum, s_w);
    k_zsum<<<dim3(BATCH, JC, 2), 192, 0, stream>>>(wsum, x, z_part);
    k_y<<<dim3(BATCH, 8), 256, 0, stream>>>(z_part, W1, b1, s_w, bias_g, out, y_part);
    k_out<<<dim3(HEADS, 4, 16), 256, 0, stream>>>(y_part, Wg, out);
}

// Round 16
// 82.401 us; speedup vs baseline: 1.0269x; 1.0269x over previous
//
#include <hip/hip_runtime.h>
#include <hip/hip_bf16.h>

#define BATCH 64
#define NNODE 512
#define D_IN 768
#define FEA 256
#define HEADS 8
#define M_ROWS (BATCH * NNODE)   // 32768
#define NEG_SLOPE 0.2f
#define LOG2E 1.4426950408889634f
#define JC 8                     // j-chunks for zsum

typedef __attribute__((ext_vector_type(4))) float f32x4;
typedef __attribute__((ext_vector_type(8))) short bf16x8;

__device__ __forceinline__ ushort f2bf(float f) {
    union { float f; unsigned u; } v; v.f = f;
    unsigned r = v.u + 0x7fffu + ((v.u >> 16) & 1u);   // RNE
    return (ushort)(r >> 16);
}
__device__ __forceinline__ short f2bf_hw(float f) {
    __hip_bfloat16 h = __float2bfloat16(f);
    return *reinterpret_cast<short*>(&h);
}
__device__ __forceinline__ float exp2fast(float v) { return __builtin_amdgcn_exp2f(v); }

// P0: was[h][f] = sum_c Wg[f, h*FEA+c] * att[h,c] — 256 blocks (full CU coverage)
__global__ __launch_bounds__(256) void k_att_proj(const float* __restrict__ Wg,
                                                  const float* __restrict__ att_src,
                                                  const float* __restrict__ att_dst,
                                                  float* __restrict__ was,
                                                  float* __restrict__ wad) {
    int h = blockIdx.x;
    const float* a = (blockIdx.y == 0) ? att_src : att_dst;
    float* o = (blockIdx.y == 0) ? was : wad;
    int wv = threadIdx.x >> 6, lane = threadIdx.x & 63;
    float4 av = *(const float4*)&a[h * FEA + lane * 4];
    int fbase = blockIdx.z * 16 + wv;
    #pragma unroll
    for (int i = 0; i < 4; i++) {
        int f = fbase + i * 4;
        float4 g = *(const float4*)&Wg[(size_t)f * (HEADS * FEA) + h * FEA + lane * 4];
        float p = g.x * av.x + g.y * av.y + g.z * av.z + g.w * av.w;
        #pragma unroll
        for (int off = 32; off; off >>= 1) p += __shfl_xor(p, off);
        if (lane == 0) o[h * FEA + f] = p;
    }
}

// P1: Bpk = W1@wv packed bf16 MFMA B-frags; c_sd = b1.wv
__global__ __launch_bounds__(256) void k_prep_was1(const float* __restrict__ W1,
                                                   const float* __restrict__ b1,
                                                   const float* __restrict__ was,
                                                   const float* __restrict__ wad,
                                                   ushort* __restrict__ Bpk,
                                                   float* __restrict__ c_sd) {
    __shared__ float wvl[16 * 260];
    __shared__ float w1l[8][256];
    __shared__ float partial[256];
    int t = threadIdx.x;
    int blk = blockIdx.x;
    int k0 = blk * 8;
    for (int i = t; i < 4096; i += 256) {
        int col = i >> 8, f = i & 255;
        wvl[col * 260 + f] = (col < 8) ? was[col * 256 + f] : wad[(col - 8) * 256 + f];
    }
    for (int i = t; i < 2048; i += 256) {
        int r = i >> 8, c = i & 255;
        w1l[r][c] = W1[(size_t)(k0 + r) * 256 + c];
    }
    __syncthreads();
    int col = t & 15, r = (t >> 4) & 7, half = t >> 7;
    float acc = 0.f;
    const float* wr = &w1l[r][half * 128];
    const float* vr = &wvl[col * 260 + half * 128];
    #pragma unroll 4
    for (int f0 = 0; f0 < 128; f0 += 4) {
        float4 a4 = *(const float4*)&wr[f0];
        float4 v4 = *(const float4*)&vr[f0];
        acc += a4.x * v4.x + a4.y * v4.y + a4.z * v4.z + a4.w * v4.w;
    }
    partial[t] = acc;
    __syncthreads();
    if (t < 128) {
        float tot = partial[t] + partial[t + 128];
        int kt = blk >> 2;
        int kloc = (blk & 3) * 8 + r;
        Bpk[kt * 1024 + ((kloc >> 3) * 16 + col) * 8 + (kloc & 7)] = f2bf(tot);
    }
    if (blk == 0 && t < 16) {
        float a = 0.f;
        for (int f = 0; f < 256; f++) a += b1[f] * wvl[t * 260 + f];
        c_sd[t] = a;
    }
}

// K1: logits = (x @ Was1 + c_sd) * LOG2E — HW bf16 cast, depth-3 reg pipeline
__global__ __launch_bounds__(256) void k_logits(const float* __restrict__ x,
                                                const ushort* __restrict__ Bpk,
                                                const float* __restrict__ c_sd,
                                                float* __restrict__ a_src,
                                                float* __restrict__ a_dst) {
    int t = threadIdx.x;
    int w = t >> 6, l = t & 63;
    int lr = l & 15, lk = l >> 4;
    int row0w = blockIdx.x * 64 + w * 16;
    const float* ap = x + (size_t)(row0w + lr) * D_IN + lk * 8;
    const ushort* bp = Bpk + l * 8;

    f32x4 A0[3], A1[3];
    bf16x8 Bf[3];
    A0[0] = *(const f32x4*)(ap);      A1[0] = *(const f32x4*)(ap + 4);
    Bf[0] = *(const bf16x8*)(bp);
    A0[1] = *(const f32x4*)(ap + 32); A1[1] = *(const f32x4*)(ap + 36);
    Bf[1] = *(const bf16x8*)(bp + 1024);
    f32x4 acc = {};

    #pragma unroll
    for (int kt = 0; kt < 24; kt++) {
        int cur = kt % 3;
        if (kt + 2 < 24) {
            int nx = (kt + 2) % 3;
            A0[nx] = *(const f32x4*)(ap + (kt + 2) * 32);
            A1[nx] = *(const f32x4*)(ap + (kt + 2) * 32 + 4);
            Bf[nx] = *(const bf16x8*)(bp + (size_t)(kt + 2) * 1024);
        }
        bf16x8 af;
        af[0] = f2bf_hw(A0[cur].x); af[1] = f2bf_hw(A0[cur].y);
        af[2] = f2bf_hw(A0[cur].z); af[3] = f2bf_hw(A0[cur].w);
        af[4] = f2bf_hw(A1[cur].x); af[5] = f2bf_hw(A1[cur].y);
        af[6] = f2bf_hw(A1[cur].z); af[7] = f2bf_hw(A1[cur].w);
        acc = __builtin_amdgcn_mfma_f32_16x16x32_bf16(af, Bf[cur], acc, 0, 0, 0);
    }
    int col = lr;
    float cadd = c_sd[col];
    float* dst = (col < 8) ? a_src : a_dst;
    int h = col & 7;
    #pragma unroll
    for (int r = 0; r < 4; r++) {
        int rr = row0w + lk * 4 + r;
        int b = rr >> 9, n = rr & 511;
        dst[((size_t)(b * 8 + h) << 9) + n] = (acc[r] + cadd) * LOG2E;
    }
}

// K2: O(N log N) softmax column-sums — single-bh, barrier-minimal (round-14 best)
__global__ __launch_bounds__(512) void k_softmax(const float* __restrict__ a_src,
                                                 const float* __restrict__ a_dst,
                                                 float* __restrict__ wout,
                                                 float* __restrict__ s_w) {
    __shared__ float s_srt[512], d_srt[512];
    __shared__ float E1[512], E2[512], PA[512], PB[512];
    __shared__ float red[8], tA[8], tB[8];
    int t = threadIdx.x;
    int lane = t & 63, wv = t >> 6;
    int bh = blockIdx.x;
    float sv = a_src[((size_t)bh << 9) + t];
    float dv = a_dst[((size_t)bh << 9) + t];
    float v_s = sv, v_d = dv;
    float mx = sv;
    #pragma unroll
    for (int off = 32; off; off >>= 1) mx = fmaxf(mx, __shfl_xor(mx, off));
    if (lane == 0) red[wv] = mx;
    __syncthreads();
    mx = red[0];
    #pragma unroll
    for (int k = 1; k < 8; k++) mx = fmaxf(mx, red[k]);
    for (int k = 2; k <= 512; k <<= 1) {
        for (int j = k >> 1; j > 0; j >>= 1) {
            bool lower = ((t & j) == 0);
            bool tmin = (lower == ((t & k) == 0));
            if (j >= 64) {
                __syncthreads();
                s_srt[t] = v_s; d_srt[t] = v_d;
                __syncthreads();
                float ps = s_srt[t ^ j], pd = d_srt[t ^ j];
                v_s = tmin ? fminf(v_s, ps) : fmaxf(v_s, ps);
                v_d = tmin ? fminf(v_d, pd) : fmaxf(v_d, pd);
            } else {
                float ps = __shfl_xor(v_s, j);
                float pd = __shfl_xor(v_d, j);
                v_s = tmin ? fminf(v_s, ps) : fmaxf(v_s, ps);
                v_d = tmin ? fminf(v_d, pd) : fmaxf(v_d, pd);
            }
        }
    }
    __syncthreads();
    s_srt[t] = v_s; d_srt[t] = v_d;
    float e1 = exp2fast(v_s - mx);
    float e2 = exp2fast(0.2f * (v_s - mx));
    #pragma unroll
    for (int off = 1; off < 64; off <<= 1) {
        float u1 = __shfl_up(e1, off);
        float u2 = __shfl_up(e2, off);
        if (lane >= off) { e1 += u1; e2 += u2; }
    }
    if (lane == 63) { tA[wv] = e1; tB[wv] = e2; }
    __syncthreads();
    float pre1 = 0.f, pre2 = 0.f, tot1 = 0.f, tot2 = 0.f;
    #pragma unroll
    for (int k = 0; k < 8; k++) {
        float a = tA[k], b = tB[k];
        tot1 += a; tot2 += b;
        if (k < wv) { pre1 += a; pre2 += b; }
    }
    e1 += pre1; e2 += pre2;
    E1[t] = e1; E2[t] = e2;
    __syncthreads();
    float v = v_d + mx;
    float mi = fmaxf(v, NEG_SLOPE * v);
    float key = -v_d;
    int lo = 0, hi = 512;
    #pragma unroll
    for (int it = 0; it < 9; it++) {
        if (lo < hi) {
            int mid = (lo + hi) >> 1;
            if (s_srt[mid] < key) lo = mid + 1; else hi = mid;
        }
    }
    float e1pre = lo ? E1[lo - 1] : 0.f;
    float e2pre = lo ? E2[lo - 1] : 0.f;
    float ga = exp2fast(v - mi);
    float gb = exp2fast(0.2f * v - mi);
    float L = ga * (tot1 - e1pre) + gb * e2pre;
    float linv = 1.f / L;
    float pa = ga * linv, pb = gb * linv;
    #pragma unroll
    for (int off = 1; off < 64; off <<= 1) {
        float u1 = __shfl_up(pa, off);
        float u2 = __shfl_up(pb, off);
        if (lane >= off) { pa += u1; pb += u2; }
    }
    __syncthreads();
    if (lane == 63) { tA[wv] = pa; tB[wv] = pb; }
    __syncthreads();
    float prp1 = 0.f, prp2 = 0.f, totp1 = 0.f, totp2 = 0.f;
    #pragma unroll
    for (int k = 0; k < 8; k++) {
        float a = tA[k], b = tB[k];
        totp1 += a; totp2 += b;
        if (k < wv) { prp1 += a; prp2 += b; }
    }
    pa += prp1; pb += prp2;
    PA[t] = pa; PB[t] = pb;
    __syncthreads();
    float key2 = -sv;
    int lo2 = 0, hi2 = 512;
    #pragma unroll
    for (int it = 0; it < 9; it++) {
        if (lo2 < hi2) {
            int mid = (lo2 + hi2) >> 1;
            if (d_srt[mid] < key2) lo2 = mid + 1; else hi2 = mid;
        }
    }
    float papre = lo2 ? PA[lo2 - 1] : 0.f;
    float pbpre = lo2 ? PB[lo2 - 1] : 0.f;
    float e1j = exp2fast(sv - mx);
    float e2j = exp2fast(0.2f * (sv - mx));
    float wj = e1j * (totp1 - papre) + e2j * pbpre;
    wout[((size_t)bh << 9) + t] = wj;
    float ssum = wj;
    #pragma unroll
    for (int off = 32; off; off >>= 1) ssum += __shfl_xor(ssum, off);
    __syncthreads();
    if (lane == 0) red[wv] = ssum;
    __syncthreads();
    if (t == 0) {
        float a = 0.f;
        #pragma unroll
        for (int k = 0; k < 8; k++) a += red[k];
        s_w[bh] = a;
    }
}

// K3: z_part[(b*JC+jc)*8+h][d] = sum_{j in 64-chunk} w[b,h,j]*x[b,j,d]
// d-split x2 for occupancy: grid (64,8,2), float2/lane, 12 waves/CU
__global__ __launch_bounds__(192) void k_zsum(const float* __restrict__ w,
                                              const float* __restrict__ x,
                                              float* __restrict__ z_part) {
    __shared__ float wl[512];   // [h][64]
    int t = threadIdx.x;
    int b = blockIdx.x, jc = blockIdx.y, dh = blockIdx.z;
    for (int i = t; i < 512; i += 192) {
        int h = i >> 6, j = i & 63;
        wl[i] = w[((size_t)(b * 8 + h) << 9) + jc * 64 + j];
    }
    __syncthreads();
    float2 acc[8] = {};
    const float* xp = x + ((size_t)(b * 512 + jc * 64)) * D_IN + dh * 384 + t * 2;
    for (int j = 0; j < 64; j++) {
        float2 xv = *(const float2*)(xp + (size_t)j * D_IN);
        #pragma unroll
        for (int h = 0; h < 8; h++) {
            float wv = wl[h * 64 + j];
            acc[h].x += wv * xv.x;
            acc[h].y += wv * xv.y;
        }
    }
    #pragma unroll
    for (int h = 0; h < 8; h++)
        *(float2*)&z_part[((size_t)((b * JC + jc) * 8 + h)) * D_IN + dh * 384 + t * 2] = acc[h];
}

// K4: y_part[ds][bh][f] = sum_{d in 96-slice} z[bh,d]*W1[d,f]  (+ s_w*b1 on ds==0)
__global__ __launch_bounds__(256) void k_y(const float* __restrict__ z_part,
                                           const float* __restrict__ W1,
                                           const float* __restrict__ b1,
                                           const float* __restrict__ s_w,
                                           const float* __restrict__ bias_g,
                                           float* __restrict__ out,
                                           float* __restrict__ y_part) {
    __shared__ float zl[8][100];
    int t = threadIdx.x;
    int b = blockIdx.x, ds = blockIdx.y;
    if (ds == 0) out[b * 256 + t] = bias_g[t];
    for (int sIdx = t; sIdx < 768; sIdx += 256) {
        int k = sIdx / 96, dd = sIdx - k * 96;
        float v = 0.f;
        #pragma unroll
        for (int jc = 0; jc < JC; jc++)
            v += z_part[((size_t)((b * JC + jc) * 8 + k)) * D_IN + ds * 96 + dd];
        zl[k][dd] = v;
    }
    __syncthreads();
    float acc[8] = {};
    for (int dq = 0; dq < 24; dq++) {
        int dbase = ds * 96 + dq * 4;
        float w0 = W1[(size_t)(dbase + 0) * 256 + t];
        float w1 = W1[(size_t)(dbase + 1) * 256 + t];
        float w2 = W1[(size_t)(dbase + 2) * 256 + t];
        float w3 = W1[(size_t)(dbase + 3) * 256 + t];
        #pragma unroll
        for (int k = 0; k < 8; k++) {
            float4 zq = *(const float4*)&zl[k][dq * 4];
            acc[k] += zq.x * w0 + zq.y * w1 + zq.z * w2 + zq.w * w3;
        }
    }
    #pragma unroll
    for (int k = 0; k < 8; k++) {
        float v = acc[k];
        if (ds == 0) v += s_w[b * 8 + k] * b1[t];
        y_part[((size_t)ds * 512 + b * 8 + k) * 256 + t] = v;
    }
}

// K5: out += (1/4096)*sum_{f slice} Y[b,h,f]*Wg[f,h*256+c] — 512 blocks
__global__ __launch_bounds__(256) void k_out(const float* __restrict__ y_part,
                                             const float* __restrict__ Wg,
                                             float* __restrict__ out) {
    __shared__ float Yl[64][5];
    int t = threadIdx.x;
    int h = blockIdx.x, fs = blockIdx.y, bq = blockIdx.z;
    int f0 = fs * 64, b0 = bq * 4;
    {
        int bl = t >> 6, fl = t & 63;
        float v = 0.f;
        #pragma unroll
        for (int ds = 0; ds < 8; ds++)
            v += y_part[((size_t)(ds * 512) + (b0 + bl) * 8 + h) * 256 + f0 + fl];
        Yl[fl][bl] = v;
    }
    __syncthreads();
    float acc[4] = {};
    #pragma unroll 4
    for (int fl = 0; fl < 64; fl++) {
        float wv = Wg[(size_t)(f0 + fl) * 2048 + h * 256 + t];
        #pragma unroll
        for (int bl = 0; bl < 4; bl++) acc[bl] += Yl[fl][bl] * wv;
    }
    #pragma unroll
    for (int bl = 0; bl < 4; bl++)
        atomicAdd(&out[(b0 + bl) * 256 + t], acc[bl] * (1.f / 4096.f));
}

extern "C" void kernel_launch(void* const* d_in, const int* in_sizes, int n_in,
                              void* d_out, int out_size, void* d_ws, size_t ws_size,
                              hipStream_t stream) {
    const float* x       = (const float*)d_in[0];
    const float* W1      = (const float*)d_in[1];
    const float* b1      = (const float*)d_in[2];
    const float* Wg      = (const float*)d_in[3];
    const float* att_src = (const float*)d_in[4];
    const float* att_dst = (const float*)d_in[5];
    const float* bias_g  = (const float*)d_in[6];
    float* out = (float*)d_out;

    float* ws       = (float*)d_ws;
    float* was      = ws;                         // 2048
    float* wad      = ws + 2048;                  // 2048
    float* c_sd     = ws + 4096;                  // 16
    ushort* Bpk     = (ushort*)(ws + 4112);       // 24576 u16 = 12288 f
    float* a_src    = ws + 16400;                 // 262144
    float* a_dst    = ws + 278544;                // 262144
    float* wsum     = ws + 540688;                // 262144
    float* s_w      = ws + 802832;                // 512
    float* z_part   = ws + 803344;                // 3145728 (64*8*8*768)
    float* y_part   = ws + 3949072;               // 1048576 (8 ds slices)

    k_att_proj<<<dim3(HEADS, 2, 16), 256, 0, stream>>>(Wg, att_src, att_dst, was, wad);
    k_prep_was1<<<96, 256, 0, stream>>>(W1, b1, was, wad, Bpk, c_sd);
    k_logits<<<M_ROWS / 64, 256, 0, stream>>>(x, Bpk, c_sd, a_src, a_dst);
    k_softmax<<<BATCH * HEADS, 512, 0, stream>>>(a_src, a_dst, wsum, s_w);
    k_zsum<<<dim3(BATCH, JC, 2), 192, 0, stream>>>(wsum, x, z_part);
    k_y<<<dim3(BATCH, 8), 256, 0, stream>>>(z_part, W1, b1, s_w, bias_g, out, y_part);
    k_out<<<dim3(HEADS, 4, 16), 256, 0, stream>>>(y_part, Wg, out);
}